// Round 15
// baseline (286.431 us; speedup 1.0000x reference)
//
#include <hip/hip_runtime.h>
#include <math.h>

typedef __fp16   h16x2 __attribute__((ext_vector_type(2)));   // cvt_pkrtz result type
typedef _Float16 f16x8 __attribute__((ext_vector_type(8)));
typedef __attribute__((ext_vector_type(4))) float f32x4;

#define KDIM 50176
#define NDIM 512
#define MDIM 512
#define BM 256
#define BN 128
#define BK 32
#define NSTEPS 1568

// packed RTZ fp16 pair
__device__ __forceinline__ unsigned pk_h(float a, float b) {
    union { h16x2 v; unsigned u; } cu;
    cu.v = __builtin_amdgcn_cvt_pkrtz(a, b);
    return cu.u;
}
// residual plane: l = rtz_fp16((a - float(h(a))) * 2048), h computed from stored value
__device__ __forceinline__ unsigned pk_l(float a, float b) {
    h16x2 hp = __builtin_amdgcn_cvt_pkrtz(a, b);
    float ra = (a - (float)hp[0]) * 2048.0f;
    float rb = (b - (float)hp[1]) * 2048.0f;
    return pk_h(ra, rb);
}

// ---- GEMM1 v5: product-split on the round-7 skeleton ----
// p=0: Ah*Wh (scale 2^-6); p=1: Ah*Wl; p=2: Al*Wh (both 2^-17).
// Wh=pk(w*2^6), Wl=pk_l(w*2^6), Ah=pk(a), Al=pk_l(a).
// Round-7 LDS (40-pitch), role-split staging, 1 barrier/step, phase-spread.
// Single acc (64 VGPR) + 60 KB LDS -> 2 independent blocks/CU.
__global__ __launch_bounds__(512, 4) void gemm1_mfma_v5(
    const float* __restrict__ A,      // [512][50176]
    const float* __restrict__ W,      // [50176][512]
    float* __restrict__ part,         // [3S][512][512]
    int steps, int S)
{
    __shared__ unsigned short Ai[2][256][40];   // single-plane A, 40-half rows, 40 KB
    __shared__ unsigned short Bi[2][128][40];   // single-plane W, 20 KB

    const int t = threadIdx.x;

    // XCD-chunked swizzle: contiguous new-l range per XCD -> each XCD owns
    // 4 full ks-slices (all 3 products, all bm/bn) for L2 reuse.
    const int nwg = 24 * S;
    int l = blockIdx.x;
    if ((nwg & 7) == 0) l = (l & 7) * (nwg >> 3) + (l >> 3);
    const int bm = l & 1, bn = (l >> 1) & 3, zf = l >> 3;   // zf in [0,3S)
    const int ks = zf / 3, p = zf - ks * 3;
    const int kbase = ks * steps * BK;
    const int bmBase = bm * BM, bnBase = bn * BN;

    const int lane = t & 63, wave = t >> 6;
    const int wm = wave >> 1, wn2 = wave & 1;   // 4x2 wave grid, 64x64 per wave
    const int l15 = lane & 15, lh = lane >> 4;

    const bool isW = (t < 256);                 // waves 0-3 stage W; 4-7 stage A
    const int u = isW ? t : (t - 256);
    const int wkb = u & 7, wn0 = (u >> 3) * 4;  // W micro: 4k x 4n
    const int achunk = u & 7, arow0 = u >> 3;   // A: rows arow0+32j, one float4 chunk

    f32x4 acc[4][4];
#pragma unroll
    for (int i = 0; i < 4; ++i)
#pragma unroll
        for (int j = 0; j < 4; ++j) acc[i][j] = (f32x4)0.f;

    float4 reg[4];                              // W: 4 float4 | A: 4 rows per half
    auto gloadW = [&](int s) {
        const float* Wb = W + (size_t)(kbase + s * BK) * NDIM + bnBase + wn0;
#pragma unroll
        for (int i = 0; i < 4; ++i)
            reg[i] = *(const float4*)(Wb + (size_t)(wkb * 4 + i) * NDIM);
    };
    auto gloadA_half = [&](int s, int half) {
        const float* Ab = A + (size_t)(bmBase + arow0 + half * 128) * KDIM
                            + kbase + s * BK + achunk * 4;
#pragma unroll
        for (int j = 0; j < 4; ++j)
            reg[j] = *(const float4*)(Ab + (size_t)(32 * j) * KDIM);
    };

    // stage one W n-row j (single plane) — consumes component j of reg[0..3]
    auto stageW = [&](int buf, int j) {
        float v0 = ((const float*)&reg[0])[j] * 64.0f;
        float v1 = ((const float*)&reg[1])[j] * 64.0f;
        float v2 = ((const float*)&reg[2])[j] * 64.0f;
        float v3 = ((const float*)&reg[3])[j] * 64.0f;
        unsigned w01, w23;
        if (p == 1) { w01 = pk_l(v0, v1); w23 = pk_l(v2, v3); }
        else        { w01 = pk_h(v0, v1); w23 = pk_h(v2, v3); }
        *(uint2*)&Bi[buf][wn0 + j][wkb * 4] = make_uint2(w01, w23);
    };
    // stage one A row (single plane) — consumes reg[j], row arow0 + half*128 + 32j
    auto stageA = [&](int buf, int half, int j) {
        float4 f = reg[j];
        unsigned w01, w23;
        if (p == 2) { w01 = pk_l(f.x, f.y); w23 = pk_l(f.z, f.w); }
        else        { w01 = pk_h(f.x, f.y); w23 = pk_h(f.z, f.w); }
        *(uint2*)&Ai[buf][arow0 + half * 128 + 32 * j][achunk * 4] = make_uint2(w01, w23);
    };

    // prologue: tile 0
    if (isW) {
        gloadW(0);
#pragma unroll
        for (int j = 0; j < 4; ++j) stageW(0, j);
    } else {
        gloadA_half(0, 0);
#pragma unroll
        for (int j = 0; j < 4; ++j) stageA(0, 0, j);
        gloadA_half(0, 1);
#pragma unroll
        for (int j = 0; j < 4; ++j) stageA(0, 1, j);
    }
    __syncthreads();

    int cur = 0;
    for (int s = 0; s < steps; ++s) {
        const bool pf = (s + 1 < steps);
        if (pf) {
            if (isW) gloadW(s + 1);
            else     gloadA_half(s + 1, 0);
        }

        // a-frags upfront (single plane, 4 x b128)
        f16x8 af[4];
#pragma unroll
        for (int mf = 0; mf < 4; ++mf)
            af[mf] = *(const f16x8*)&Ai[cur][wm * 64 + mf * 16 + l15][lh * 8];
        // b-frags one-ahead
        f16x8 bf[2];
        bf[0] = *(const f16x8*)&Bi[cur][wn2 * 64 + l15][lh * 8];

#pragma unroll
        for (int nf = 0; nf < 4; ++nf) {
            const int c = nf & 1, n = c ^ 1;
            if (nf < 3)
                bf[n] = *(const f16x8*)&Bi[cur][wn2 * 64 + (nf + 1) * 16 + l15][lh * 8];
            __builtin_amdgcn_s_setprio(1);
#pragma unroll
            for (int mf = 0; mf < 4; ++mf)
                acc[mf][nf] = __builtin_amdgcn_mfma_f32_16x16x32_f16(af[mf], bf[c], acc[mf][nf], 0, 0, 0);
            __builtin_amdgcn_s_setprio(0);
            if (pf) {
                if (isW) {
                    stageW(cur ^ 1, nf);               // 1 n-row per phase
                } else {
                    const int half = nf >> 1, j0 = (nf & 1) * 2;
                    stageA(cur ^ 1, half, j0);         // 2 rows per phase
                    stageA(cur ^ 1, half, j0 + 1);
                    if (nf == 1) gloadA_half(s + 1, 1); // issue 2nd half mid-step
                }
            }
        }
        __syncthreads();
        cur ^= 1;
    }

    const float scale = (p == 0) ? (1.0f / 64.0f) : (1.0f / 131072.0f);
    float* Cp = part + (size_t)zf * (MDIM * NDIM);
    const int row0 = bmBase + wm * 64;
    const int col0 = bnBase + wn2 * 64;
#pragma unroll
    for (int mf = 0; mf < 4; ++mf)
#pragma unroll
        for (int nf = 0; nf < 4; ++nf) {
            const int r0 = row0 + mf * 16 + lh * 4;
            const int c = col0 + nf * 16 + l15;
#pragma unroll
            for (int r = 0; r < 4; ++r)
                Cp[(size_t)(r0 + r) * NDIM + c] = acc[mf][nf][r] * scale;
        }
}

// ---------------- reduce partials + bias + relu -> h1 (float4) ----------------
__global__ __launch_bounds__(256) void reduce_bias_relu(
    const float4* __restrict__ part, const float* __restrict__ b1,
    float4* __restrict__ h1, int zsl)
{
    int i = blockIdx.x * 256 + threadIdx.x;      // 0..65535 float4s
    float4 s = make_float4(0.f, 0.f, 0.f, 0.f);
    for (int z = 0; z < zsl; ++z) {
        float4 v = part[(size_t)z * 65536 + i];
        s.x += v.x; s.y += v.y; s.z += v.z; s.w += v.w;
    }
    int nb = (i & 127) * 4;
    s.x = fmaxf(s.x + b1[nb + 0], 0.f);
    s.y = fmaxf(s.y + b1[nb + 1], 0.f);
    s.z = fmaxf(s.z + b1[nb + 2], 0.f);
    s.w = fmaxf(s.w + b1[nb + 3], 0.f);
    h1[i] = s;
}

// ---------------- layer 2: h2 = relu(h1 @ W2 + b2) ----------------
__global__ __launch_bounds__(256) void gemm2_k(
    const float* __restrict__ h1, const float* __restrict__ W2,
    const float* __restrict__ b2, float* __restrict__ h2)
{
    int g = blockIdx.x * 256 + threadIdx.x;     // 0..131071
    int m = g >> 8, n = g & 255;
    const float* a = h1 + (size_t)m * 512;
    float sum = 0.f;
#pragma unroll 8
    for (int k = 0; k < 512; ++k) sum = fmaf(a[k], W2[(size_t)k * 256 + n], sum);
    sum += b2[n];
    h2[g] = fmaxf(sum, 0.f);
}

// ---------------- layer 3: pred = sigmoid(h2 @ W3 + b3) ----------------
__global__ __launch_bounds__(256) void gemm3_sig(
    const float* __restrict__ h2, const float* __restrict__ W3,
    const float* __restrict__ b3, float* __restrict__ pred)
{
    int g = blockIdx.x * 256 + threadIdx.x;     // 0..8191
    int m = g >> 4, j = g & 15;
    const float* a = h2 + (size_t)m * 256;
    float sum = 0.f;
#pragma unroll 8
    for (int k = 0; k < 256; ++k) sum = fmaf(a[k], W3[(size_t)k * 16 + j], sum);
    sum += b3[j];
    pred[g] = 1.f / (1.f + expf(-sum));
}

// ---------------- patch gathers ----------------
__device__ __forceinline__ int clip_coord(float v) {
    int c = (int)(v * 224.0f);
    if (c >= 219) c = 200;
    if (c <= 5)   c = 8;
    return c;
}

__global__ void patches_k(
    const float* __restrict__ pm, const float* __restrict__ gt,
    const float* __restrict__ pred, float* __restrict__ out)
{
    const int b = blockIdx.x;
    const int t = threadIdx.x;          // 0..287
    const int lm = t / 36, cell = t % 36;
    const int dx = cell / 6 - 3, dy = cell % 6 - 3;
    const float* pmb = pm + (size_t)b * 50176;
    {
        int cx = clip_coord(gt[b * 16 + lm * 2 + 0]);
        int cy = clip_coord(gt[b * 16 + lm * 2 + 1]);
        out[8192 + b * 288 + t] = pmb[(cx + dx) * 224 + (cy + dy)];
    }
    {
        int cx = clip_coord(pred[b * 16 + lm * 2 + 0]);
        int cy = clip_coord(pred[b * 16 + lm * 2 + 1]);
        out[8192 + 147456 + b * 288 + t] = pmb[(cx + dx) * 224 + (cy + dy)];
    }
}

extern "C" void kernel_launch(void* const* d_in, const int* in_sizes, int n_in,
                              void* d_out, int out_size, void* d_ws, size_t ws_size,
                              hipStream_t stream)
{
    const float* pred_map = (const float*)d_in[0];
    const float* gt       = (const float*)d_in[1];
    const float* W1       = (const float*)d_in[2];
    const float* b1       = (const float*)d_in[3];
    const float* W2       = (const float*)d_in[4];
    const float* b2       = (const float*)d_in[5];
    const float* W3       = (const float*)d_in[6];
    const float* b3       = (const float*)d_in[7];
    float* out = (float*)d_out;

    float* h1   = (float*)d_ws;          // 262144 floats
    float* h2   = h1 + 262144;           // 131072 floats
    float* part = h2 + 131072;           // 3S * 262144 floats

    // largest S (dividing 1568) whose 3S partial slices fit the workspace
    static const int cand[] = {32, 16, 8, 4, 2, 1};
    int S = 1;
    for (int i = 0; i < 6; ++i) {
        size_t need = (size_t)(393216 + (size_t)(3 * cand[i]) * 262144) * sizeof(float);
        if (need <= ws_size) { S = cand[i]; break; }
    }
    const int steps = NSTEPS / S;
    const int zsl = 3 * S;

    hipLaunchKernelGGL(gemm1_mfma_v5, dim3(8 * zsl), dim3(512), 0, stream,
                       pred_map, W1, part, steps, S);
    hipLaunchKernelGGL(reduce_bias_relu, dim3(256), dim3(256), 0, stream,
                       (const float4*)part, b1, (float4*)h1, zsl);
    hipLaunchKernelGGL(gemm2_k, dim3(131072 / 256), dim3(256), 0, stream, h1, W2, b2, h2);
    hipLaunchKernelGGL(gemm3_sig, dim3(8192 / 256), dim3(256), 0, stream, h2, W3, b3, out);
    hipLaunchKernelGGL(patches_k, dim3(512), dim3(288), 0, stream, pred_map, gt, out, out);
}